// Round 5
// baseline (572.609 us; speedup 1.0000x reference)
//
#include <hip/hip_runtime.h>
#include <math.h>
#include <stdint.h>

#define DI __device__ __forceinline__
typedef unsigned short u16;
typedef unsigned int   u32;
typedef unsigned long long u64;

typedef __attribute__((ext_vector_type(4)))  float f32x4;
typedef __attribute__((ext_vector_type(16))) float f32x16;
typedef __attribute__((ext_vector_type(8)))  short bf16x8;

DI float bf2f(u16 v){ return __uint_as_float(((u32)v) << 16); }
DI u16 f2bf(float f){ u32 u = __float_as_uint(f); return (u16)((u + 0x7FFFu + ((u >> 16) & 1u)) >> 16); }
DI u32 pack2(float re, float im){ return (u32)f2bf(re) | ((u32)f2bf(im) << 16); }

// tanh-form GELU: v*sigmoid(2z), z = sqrt(2/pi)(v+0.044715v^3). Max |err| vs exact
// erf-GELU ~5e-4 (budget 0.11). ~9 VALU incl one v_exp. z clamped: exp overflow guard.
DI float gelu_fast(float v){
  float t = v * v;
  float z = v * fmaf(0.0356774081f, t, 0.7978845608f);
  z = fminf(z, 15.0f);
  float e = __expf(2.0f * z);
  return v * e * __frcp_rn(1.0f + e);
}

// ---------------- tiled transposes (coalesced both sides) ----------------
__global__ __launch_bounds__(256) void transpose_u32(const u32* __restrict__ in, u32* __restrict__ out, int R, int C){
  __shared__ u32 tile[64][65];
  int t = threadIdx.x;
  int c = t & 63, r0 = t >> 6;
  size_t bofs = (size_t)blockIdx.z * (size_t)R * (size_t)C;
  const u32* ib = in  + bofs + (size_t)(blockIdx.y * 64) * C + blockIdx.x * 64;
  u32*       ob = out + bofs + (size_t)(blockIdx.x * 64) * R + blockIdx.y * 64;
  #pragma unroll
  for (int i = 0; i < 16; i++){ int r = r0 + i * 4; tile[r][c] = ib[(size_t)r * C + c]; }
  __syncthreads();
  #pragma unroll
  for (int i = 0; i < 16; i++){ int r = r0 + i * 4; ob[(size_t)r * R + c] = tile[c][r]; }
}

// fp32 in -> bf16 transposed out (weights: KxN -> NxK bf16)
__global__ __launch_bounds__(256) void transpose_f32_bf16(const float* __restrict__ in, u16* __restrict__ out, int R, int C){
  __shared__ u16 tile[64][65];
  int t = threadIdx.x;
  int c = t & 63, r0 = t >> 6;
  const float* ib = in  + (size_t)(blockIdx.y * 64) * C + blockIdx.x * 64;
  u16*         ob = out + (size_t)(blockIdx.x * 64) * R + blockIdx.y * 64;
  #pragma unroll
  for (int i = 0; i < 16; i++){ int r = r0 + i * 4; tile[r][c] = f2bf(ib[(size_t)r * C + c]); }
  __syncthreads();
  #pragma unroll
  for (int i = 0; i < 16; i++){ int r = r0 + i * 4; ob[(size_t)r * R + c] = tile[c][r]; }
}

// ---------------- radix-4 Stockham FFT in LDS (float2 AoS, b64 DS ops) ----------------
template<int LOGN>
DI float2* fft_r4(float2* s, float2* d, int t){
  const int Q = 1 << (LOGN - 2);
  #pragma unroll
  for (int st = 0; st < (LOGN >> 1); ++st){
    const int m = 1 << (2 * st);
    const float ang = -6.28318530717958647692f * (float)m / (float)(1 << LOGN);
    #pragma unroll
    for (int j0 = 0; j0 < Q; j0 += 256){
      int j = j0 + t;
      int p = j >> (2 * st);
      int q = j & (m - 1);
      int o = q + (p << (2 * st + 2));
      float2 a0 = s[j], a1 = s[j + Q], a2 = s[j + 2 * Q], a3 = s[j + 3 * Q];
      float s0r = a0.x + a2.x, s0i = a0.y + a2.y, d0r = a0.x - a2.x, d0i = a0.y - a2.y;
      float s1r = a1.x + a3.x, s1i = a1.y + a3.y, d1r = a1.x - a3.x, d1i = a1.y - a3.y;
      float sn, cs; __sincosf(ang * (float)p, &sn, &cs);
      float t2r = cs * cs - sn * sn, t2i = 2.f * cs * sn;
      float t3r = t2r * cs - t2i * sn, t3i = t2r * sn + t2i * cs;
      float e1r = d0r + d1i, e1i = d0i - d1r;
      float e2r = s0r - s1r, e2i = s0i - s1i;
      float e3r = d0r - d1i, e3i = d0i + d1r;
      d[o]         = make_float2(s0r + s1r, s0i + s1i);
      d[o + m]     = make_float2(cs * e1r - sn * e1i,  cs * e1i + sn * e1r);
      d[o + 2 * m] = make_float2(t2r * e2r - t2i * e2i, t2r * e2i + t2i * e2r);
      d[o + 3 * m] = make_float2(t3r * e3r - t3i * e3i, t3r * e3i + t3i * e3r);
    }
    __syncthreads();
    float2* tp = s; s = d; d = tp;
  }
  return s;
}

// K1: packed real FFT over seq. Block g handles rows 2g,2g+1 of xT as z=xa+i*xb.
__global__ __launch_bounds__(256) void fft_seq(const float* __restrict__ xT, u32* __restrict__ ZT2,
                                               float* __restrict__ Zny){
  __shared__ float2 A[4096], Bb[4096];  // 64 KB
  int t = threadIdx.x, g = blockIdx.x;  // g in [0,2048)
  const float* r0 = xT + (size_t)(2 * g) * 4096;
  #pragma unroll
  for (int i = 0; i < 4; i++){
    int idx = i * 1024 + t * 4;
    float4 va = *(const float4*)(r0 + idx);
    float4 vb = *(const float4*)(r0 + 4096 + idx);
    A[idx + 0] = make_float2(va.x, vb.x);
    A[idx + 1] = make_float2(va.y, vb.y);
    A[idx + 2] = make_float2(va.z, vb.z);
    A[idx + 3] = make_float2(va.w, vb.w);
  }
  __syncthreads();
  float2* R = fft_r4<12>(A, Bb, t);
  size_t ob0 = (size_t)(2 * g) * 2048;
  #pragma unroll
  for (int i = 0; i < 2; i++){
    int k0 = i * 1024 + t * 4;
    u32 wa[4], wb[4];
    #pragma unroll
    for (int kk = 0; kk < 4; kk++){
      int k = k0 + kk, m = (4096 - k) & 4095;
      float2 zk = R[k], zm = R[m];
      wa[kk] = pack2(0.5f * (zk.x + zm.x), 0.5f * (zk.y - zm.y));   // Xa = (Z+conj(Zm))/2
      wb[kk] = pack2(0.5f * (zk.y + zm.y), 0.5f * (zm.x - zk.x));   // Xb = -i(Z-conj(Zm))/2
    }
    *(uint4*)(ZT2 + ob0 + k0)        = make_uint4(wa[0], wa[1], wa[2], wa[3]);
    *(uint4*)(ZT2 + ob0 + 2048 + k0) = make_uint4(wb[0], wb[1], wb[2], wb[3]);
  }
  if (t == 0){ float2 z = R[2048]; Zny[2 * g] = z.x; Zny[2 * g + 1] = z.y; }
}

DI void block_stats4(float a1, float a2, float b1, float b2, int t,
                     float& mA, float& iA, float& mB, float& iB){
  __shared__ float sh[4][4];
  #pragma unroll
  for (int o = 32; o > 0; o >>= 1){
    a1 += __shfl_down(a1, o); a2 += __shfl_down(a2, o);
    b1 += __shfl_down(b1, o); b2 += __shfl_down(b2, o);
  }
  if ((t & 63) == 0){ int w = t >> 6; sh[w][0] = a1; sh[w][1] = a2; sh[w][2] = b1; sh[w][3] = b2; }
  __syncthreads();
  float SA = sh[0][0] + sh[1][0] + sh[2][0] + sh[3][0];
  float QA = sh[0][1] + sh[1][1] + sh[2][1] + sh[3][1];
  float SB = sh[0][2] + sh[1][2] + sh[2][2] + sh[3][2];
  float QB = sh[0][3] + sh[1][3] + sh[2][3] + sh[3][3];
  mA = SA * (1.f / 1024.f); iA = rsqrtf(QA * (1.f / 1024.f) - mA * mA + 1e-5f);
  mB = SB * (1.f / 1024.f); iB = rsqrtf(QB * (1.f / 1024.f) - mB * mB + 1e-5f);
}

// K2: hidden FFT for k=0..2048 (Hermitian mirror gives row 4096-k), +x residual, LN1 -> h (bf16)
__global__ __launch_bounds__(256) void fft_hid_ln(const u32* __restrict__ Z2, const float* __restrict__ Zny,
    const float* __restrict__ x, const float* __restrict__ g1, const float* __restrict__ be1,
    u16* __restrict__ h){
  __shared__ float2 A[1024], Bb[1024];  // 16 KB
  int t = threadIdx.x, id = blockIdx.x;
  int b = id / 2049, k = id - b * 2049;
  int idx = t * 4;
  if (k == 2048){
    float4 v = *(const float4*)(Zny + b * 1024 + idx);
    A[idx + 0] = make_float2(v.x, 0.f); A[idx + 1] = make_float2(v.y, 0.f);
    A[idx + 2] = make_float2(v.z, 0.f); A[idx + 3] = make_float2(v.w, 0.f);
  } else {
    uint4 zv = *(const uint4*)(Z2 + ((size_t)b * 2048 + k) * 1024 + idx);
    A[idx + 0] = make_float2(bf2f((u16)(zv.x & 0xffffu)), bf2f((u16)(zv.x >> 16)));
    A[idx + 1] = make_float2(bf2f((u16)(zv.y & 0xffffu)), bf2f((u16)(zv.y >> 16)));
    A[idx + 2] = make_float2(bf2f((u16)(zv.z & 0xffffu)), bf2f((u16)(zv.z >> 16)));
    A[idx + 3] = make_float2(bf2f((u16)(zv.w & 0xffffu)), bf2f((u16)(zv.w >> 16)));
  }
  __syncthreads();
  float2* R = fft_r4<10>(A, Bb, t);
  int rowA = b * 4096 + k;
  bool two = (k >= 1) && (k <= 2047);
  int rowB = b * 4096 + (4096 - k);
  float4 xa = *(const float4*)(x + (size_t)rowA * 1024 + idx);
  float vA0 = R[idx + 0].x + xa.x, vA1 = R[idx + 1].x + xa.y;
  float vA2 = R[idx + 2].x + xa.z, vA3 = R[idx + 3].x + xa.w;
  float vB0 = 0.f, vB1 = 0.f, vB2 = 0.f, vB3 = 0.f;
  if (two){
    float4 xb = *(const float4*)(x + (size_t)rowB * 1024 + idx);
    vB0 = R[(1024 - (idx + 0)) & 1023].x + xb.x;   // Re(Y[4096-k,m]) = Re(Y[k,(1024-m)&1023])
    vB1 = R[(1024 - (idx + 1)) & 1023].x + xb.y;
    vB2 = R[(1024 - (idx + 2)) & 1023].x + xb.z;
    vB3 = R[(1024 - (idx + 3)) & 1023].x + xb.w;
  }
  float mA, iA, mB, iB;
  block_stats4(vA0 + vA1 + vA2 + vA3, vA0 * vA0 + vA1 * vA1 + vA2 * vA2 + vA3 * vA3,
               vB0 + vB1 + vB2 + vB3, vB0 * vB0 + vB1 * vB1 + vB2 * vB2 + vB3 * vB3,
               t, mA, iA, mB, iB);
  float4 gv = *(const float4*)(g1 + idx);
  float4 bv = *(const float4*)(be1 + idx);
  ushort4 oA;
  oA.x = f2bf((vA0 - mA) * iA * gv.x + bv.x);
  oA.y = f2bf((vA1 - mA) * iA * gv.y + bv.y);
  oA.z = f2bf((vA2 - mA) * iA * gv.z + bv.z);
  oA.w = f2bf((vA3 - mA) * iA * gv.w + bv.w);
  *(ushort4*)(h + (size_t)rowA * 1024 + idx) = oA;
  if (two){
    ushort4 oB;
    oB.x = f2bf((vB0 - mB) * iB * gv.x + bv.x);
    oB.y = f2bf((vB1 - mB) * iB * gv.y + bv.y);
    oB.z = f2bf((vB2 - mB) * iB * gv.z + bv.z);
    oB.w = f2bf((vB3 - mB) * iB * gv.w + bv.w);
    *(ushort4*)(h + (size_t)rowB * 1024 + idx) = oB;
  }
}

// K3: final LayerNorm on y rows (bf16) -> out (fp32)
__global__ __launch_bounds__(256) void ln_rows(const u16* __restrict__ yv, const float* __restrict__ g,
    const float* __restrict__ be, float* __restrict__ o){
  int t = threadIdx.x;
  size_t base = (size_t)blockIdx.x * 1024;
  int idx = t * 4;
  ushort4 v4 = *(const ushort4*)(yv + base + idx);
  float v0 = bf2f(v4.x), v1 = bf2f(v4.y), v2 = bf2f(v4.z), v3 = bf2f(v4.w);
  float mA, iA, mB, iB;
  block_stats4(v0 + v1 + v2 + v3, v0 * v0 + v1 * v1 + v2 * v2 + v3 * v3, 0.f, 0.f, t, mA, iA, mB, iB);
  float4 gv = *(const float4*)(g + idx);
  float4 bv = *(const float4*)(be + idx);
  float4 ov;
  ov.x = (v0 - mA) * iA * gv.x + bv.x;
  ov.y = (v1 - mA) * iA * gv.y + bv.y;
  ov.z = (v2 - mA) * iA * gv.z + bv.z;
  ov.w = (v3 - mA) * iA * gv.w + bv.w;
  *(float4*)(o + base + idx) = ov;
}

// ======================= persistent 256x256 8-phase bf16 GEMM (32x32x16 MFMA) ===========
// r5: single-variable switch 16x16x32 -> 32x32x16 (m119: 2495 vs 2176 TF pipe ceiling,
// half the MFMA instruction count at identical LDS traffic). Per wave: acc[4 mfb][2 nfb]
// f32x16 (same 128 VGPR); A-frag lane layout A[row=ln&31][k=8*(ln>>5)..+7]; frag chunk
// index = (kk<<1)|(ln>>5), XOR'd by the same (row>>1)&3 swizzle (stage side unchanged).
// C/D: col=ln&31, row=(reg&3)+8*(reg>>2)+4*(ln>>5)  [m74/m101-verified].
// Phases (reads 12/0/12/0; 8 MFMA each; stage placement + counted vmcnt(6) unchanged):
//   P0{rd ks0 x12; stage B(kt+1)ks1; bar; MFMA ks0 nfb0; bar}
//   P1{            stage A(kt+2)ks0; bar; MFMA ks0 nfb1; bar}
//   P2{rd ks1 x12; stage B(kt+2)ks0; bar; MFMA ks1 nfb0; bar}
//   P3{            stage A(kt+2)ks1; bar; MFMA ks1 nfb1; vmcnt(6); bar}
// Overwrite-safety: every ds_read of a region retires at the data-dependent lgkm wait
// before its consuming MFMA cluster, which precedes the region's overwriting stage by
// >=1 barrier in all four cases (A-ks0: read P0/used P0-P1 MFMA < stage P1-lands-later;
// B-ks0: used<=P1 < stage P2; A-ks1/B-ks1: used<=P3 < stage P3-later/next-P0).
// PERSISTENT + prestage-before-epilogue + partitions (gemm1 GN=4, gemm2 GN=1) unchanged.
typedef const __attribute__((address_space(1))) void* as1cp;
typedef __attribute__((address_space(3))) void* as3p;
DI void async_copy16(const void* g, void* l){
  __builtin_amdgcn_global_load_lds((as1cp)(u64)g, (as3p)(u32)(u64)l, 16, 0, 0);
}
DI void bar(){
  asm volatile("" ::: "memory");
  __builtin_amdgcn_s_barrier();
  asm volatile("" ::: "memory");
}

template<int DOGELU>
__global__ __launch_bounds__(512, 2) void gemm256(const u16* __restrict__ A, const u16* __restrict__ Bm,
    const float* __restrict__ bias, const u16* __restrict__ resid, u16* __restrict__ C,
    int M, int N, int K, int gn_shift, int npg_shift, int mpg, int bpg, int npt)
{
  __shared__ u16 sA[2][2][8192];   // [buf][ks][256 rows x 32 k]
  __shared__ u16 sB[2][2][8192];
  int t = threadIdx.x, wv = t >> 6, ln = t & 63;

  int bid = blockIdx.x;
  int c8 = bid & 7, j0 = bid >> 3;
  int ng = c8 & ((1 << gn_shift) - 1);
  int mg = c8 >> gn_shift;
  int npg_m1 = (1 << npg_shift) - 1;

  int wm = wv >> 2, wn = wv & 3;       // wave -> (m-half, n-quarter) of the 256x256 tile
  int l32 = ln & 31, hi = ln >> 5;
  // frag ds_read bases: row = ln&31 within 32-row block; chunk' = ((kk<<1)|hi) ^ ((row>>1)&3)
  int swzl = (ln >> 1) & 3;            // == ((ln&31)>>1)&3 for all ln
  int cb0 = ((0 | hi) ^ swzl) << 3;    // kk=0 chunk offset (u16 units)
  int cb1 = ((2 | hi) ^ swzl) << 3;    // kk=1
  int abase = (wm * 128 + l32) * 32;
  int bbase = (wn * 64  + l32) * 32;
  int srow = wv * 32 + (ln >> 2);
  int gch  = ((ln & 3) ^ ((srow >> 1) & 3)) << 3;     // inverse swizzle on global source
  int ldof = wv * 1024 + ln * 8;
  int NT = K >> 6;

  #define STAGE(g0, g1, kc, unit) do{ \
    async_copy16((g0) + (kc), (unit) + ldof); \
    async_copy16((g1) + (kc), (unit) + 512 + ldof); }while(0)
  #define PROLOGUE() do{ \
    STAGE(gA0, gA1, 0,  &sA[0][0][0]); \
    STAGE(gB0, gB1, 0,  &sB[0][0][0]); \
    STAGE(gA0, gA1, 32, &sA[0][1][0]); \
    STAGE(gB0, gB1, 32, &sB[0][1][0]); \
    STAGE(gA0, gA1, 64, &sA[1][0][0]); \
    STAGE(gB0, gB1, 64, &sB[1][0][0]); \
    STAGE(gA0, gA1, 96, &sA[1][1][0]); }while(0)
  #define RD12(src_a, src_b) do{ \
    _Pragma("unroll") \
    for (int mfb = 0; mfb < 4; mfb++){ \
      af[mfb]     = *(const bf16x8*)((src_a) + abase + mfb * 1024 + cb0); \
      af[4 + mfb] = *(const bf16x8*)((src_a) + abase + mfb * 1024 + cb1); \
    } \
    bf[0] = *(const bf16x8*)((src_b) + bbase + cb0); \
    bf[1] = *(const bf16x8*)((src_b) + bbase + cb1); \
    bf[2] = *(const bf16x8*)((src_b) + bbase + 1024 + cb0); \
    bf[3] = *(const bf16x8*)((src_b) + bbase + 1024 + cb1); }while(0)
  // MFMA cluster: one nfb, both kk (acc chain distance 4)
  #define MM8(nfb) do{ \
    _Pragma("unroll") \
    for (int mfb = 0; mfb < 4; mfb++) \
      acc[mfb][nfb] = __builtin_amdgcn_mfma_f32_32x32x16_bf16(af[mfb], bf[2*(nfb)], acc[mfb][nfb], 0, 0, 0); \
    _Pragma("unroll") \
    for (int mfb = 0; mfb < 4; mfb++) \
      acc[mfb][nfb] = __builtin_amdgcn_mfma_f32_32x32x16_bf16(af[4 + mfb], bf[2*(nfb) + 1], acc[mfb][nfb], 0, 0, 0); }while(0)

  // tile 0 pointers + initial prologue
  int jt = j0;
  int n0 = (((ng << npg_shift) + (jt & npg_m1)) << 8);
  int m0 = ((mg * mpg + (jt >> npg_shift)) << 8);
  const u16* gA0 = A  + (size_t)(m0 + srow) * K + gch;
  const u16* gA1 = gA0 + (size_t)16 * K;
  const u16* gB0 = Bm + (size_t)(n0 + srow) * K + gch;
  const u16* gB1 = gB0 + (size_t)16 * K;
  PROLOGUE();
  asm volatile("s_waitcnt vmcnt(6)" ::: "memory");   // tile0 resident; tile1 in flight
  bar();

  for (int s = 0; s < npt; ++s){
    f32x16 acc[4][2];
    #pragma unroll
    for (int mfb = 0; mfb < 4; mfb++)
      #pragma unroll
      for (int nfb = 0; nfb < 2; nfb++)
        acc[mfb][nfb] = (f32x16)(0.f);

    for (int kt = 0; kt < NT; ++kt){
      int buf = kt & 1;
      u16* a0s = &sA[buf][0][0];
      u16* a1s = &sA[buf][1][0];
      u16* b0s = &sB[buf][0][0];
      u16* b1s = &sB[buf][1][0];
      u16* bn1 = &sB[buf ^ 1][1][0];     // B(kt+1)-ks1 dest (other buf)
      bool st1 = (kt + 1) < NT;
      bool st2 = (kt + 2) < NT;
      int kb1 = (kt + 1) << 6, kb2 = (kt + 2) << 6;
      bf16x8 af[8], bf[4];

      // ---- P0: rd ks0 x12; stage B(kt+1)ks1; MFMA (ks0, nfb0)
      RD12(a0s, b0s);
      if (st1) STAGE(gB0, gB1, kb1 + 32, bn1);
      bar();
      __builtin_amdgcn_s_setprio(1);
      MM8(0);
      __builtin_amdgcn_s_setprio(0);
      bar();

      // ---- P1: stage A(kt+2)ks0; MFMA (ks0, nfb1)
      if (st2) STAGE(gA0, gA1, kb2, a0s);
      bar();
      __builtin_amdgcn_s_setprio(1);
      MM8(1);
      __builtin_amdgcn_s_setprio(0);
      bar();

      // ---- P2: rd ks1 x12; stage B(kt+2)ks0; MFMA (ks1, nfb0)
      RD12(a1s, b1s);
      if (st2) STAGE(gB0, gB1, kb2, b0s);
      bar();
      __builtin_amdgcn_s_setprio(1);
      MM8(0);
      __builtin_amdgcn_s_setprio(0);
      bar();

      // ---- P3: stage A(kt+2)ks1; MFMA (ks1, nfb1); boundary vmcnt
      if (st2) STAGE(gA0, gA1, kb2 + 32, a1s);
      bar();
      __builtin_amdgcn_s_setprio(1);
      MM8(1);
      __builtin_amdgcn_s_setprio(0);
      if (st2) asm volatile("s_waitcnt vmcnt(6)" ::: "memory");  // tile kt+1 landed; 3 units in flight
      else     asm volatile("s_waitcnt vmcnt(0)" ::: "memory");  // tail: drain before LDS reuse
      bar();
    }

    // prestage tile s+1 BEFORE epilogue: staging latency hides under epilogue VALU.
    int em0 = m0, en0 = n0;
    if (s + 1 < npt){
      jt = j0 + (s + 1) * bpg;
      n0 = (((ng << npg_shift) + (jt & npg_m1)) << 8);
      m0 = ((mg * mpg + (jt >> npg_shift)) << 8);
      gA0 = A  + (size_t)(m0 + srow) * K + gch;
      gA1 = gA0 + (size_t)16 * K;
      gB0 = Bm + (size_t)(n0 + srow) * K + gch;
      gB1 = gB0 + (size_t)16 * K;
      PROLOGUE();
    }

    // epilogue: 32x32 D mapping: col=ln&31, row=(reg&3)+8*(reg>>2)+4*(ln>>5)
    #pragma unroll
    for (int mfb = 0; mfb < 4; mfb++){
      #pragma unroll
      for (int nfb = 0; nfb < 2; nfb++){
        int col = en0 + wn * 64 + nfb * 32 + l32;
        float bv = bias[col];
        #pragma unroll
        for (int g4 = 0; g4 < 4; g4++){
          #pragma unroll
          for (int i = 0; i < 4; i++){
            int row_l = i + 8 * g4 + 4 * hi;
            int mr = em0 + wm * 128 + mfb * 32 + row_l;
            float v = acc[mfb][nfb][g4 * 4 + i] + bv;
            if (DOGELU){
              v = gelu_fast(v);
            } else {
              v += bf2f(resid[(size_t)mr * N + col]);
            }
            C[(size_t)mr * N + col] = f2bf(v);
          }
        }
      }
    }

    if (s + 1 < npt){
      // in-order vmcnt retirement: waiting to <=6 retires all 14 prestage instrs
      // (older than the epilogue stores); the 6 left in flight are newest stores.
      asm volatile("s_waitcnt vmcnt(6)" ::: "memory");
      bar();
    }
  }
  #undef MM8
  #undef RD12
  #undef PROLOGUE
  #undef STAGE
}

// ---------------- orchestration ----------------
// B=4, S=4096, H=1024, fp32 I/O. ws >= 209 MiB proven (round-3 nch=1 FETCH signature).
static inline int ilog2(int v){ int s = 0; while ((1 << s) < v) ++s; return s; }

extern "C" void kernel_launch(void* const* d_in, const int* in_sizes, int n_in,
                              void* d_out, int out_size, void* d_ws, size_t ws_size,
                              hipStream_t stream){
  const float* x   = (const float*)d_in[0];
  const float* w1  = (const float*)d_in[1];
  const float* b1  = (const float*)d_in[2];
  const float* w2  = (const float*)d_in[3];
  const float* b2  = (const float*)d_in[4];
  const float* g1  = (const float*)d_in[5];
  const float* be1 = (const float*)d_in[6];
  const float* g2  = (const float*)d_in[7];
  const float* be2 = (const float*)d_in[8];
  float* out = (float*)d_out;
  char* ws = (char*)d_ws;
  const size_t MB = (size_t)1 << 20;
  float* xT  = (float*)(ws);
  u32*  ZT2  = (u32*)(ws + 64 * MB);
  float* Zny = (float*)(ws + 96 * MB);
  u32*  Z2   = (u32*)(ws);
  u16*  h    = (u16*)(ws + 32 * MB);
  u16*  w1T  = (u16*)(ws + 64 * MB);
  u16*  w2T  = (u16*)(ws + 72 * MB);
  u16*  u    = (u16*)(ws + 80 * MB);
  u16*  y    = (u16*)(ws);
  dim3 blk(256, 1, 1);
  dim3 blk2(512, 1, 1);

  // mixing: seq FFT (packed real pairs) -> Hermitian half -> hidden FFT (+x, LN1)
  transpose_u32<<<dim3(16, 64, 4), blk, 0, stream>>>((const u32*)x, (u32*)xT, 4096, 1024);
  fft_seq      <<<dim3(2048, 1, 1), blk, 0, stream>>>(xT, ZT2, Zny);
  transpose_u32<<<dim3(32, 16, 4), blk, 0, stream>>>(ZT2, Z2, 1024, 2048);
  fft_hid_ln   <<<dim3(4 * 2049, 1, 1), blk, 0, stream>>>(Z2, Zny, x, g1, be1, h);

  // FFN
  transpose_f32_bf16<<<dim3(64, 16, 1), blk, 0, stream>>>(w1, w1T, 1024, 4096);
  transpose_f32_bf16<<<dim3(16, 64, 1), blk, 0, stream>>>(w2, w2T, 4096, 1024);
  int nch = (ws_size >= (size_t)209 * MB) ? 1 : (ws_size >= (size_t)145 * MB) ? 2 : 4;
  int Mc = 16384 / nch;
  for (int ch = 0; ch < nch; ++ch){
    const u16* hch = h + (size_t)ch * Mc * 1024;
    u16* ych = y + (size_t)ch * Mc * 1024;
    // gemm1: M x 4096, K=1024, GN=4 n-groups (B-slice 2MB L2-locked)
    {
      int tm = Mc >> 8, tn = 16, gn = 2;
      int tiles = tm * tn;
      int grid = tiles < 256 ? tiles : 256;
      int npt = tiles / grid, bpg = grid >> 3;
      int npgs = ilog2(tn >> gn);
      int mpg = tm >> (3 - gn);
      gemm256<1><<<dim3(grid), blk2, 0, stream>>>(hch, w1T, b1, (const u16*)nullptr, u,
                                                  Mc, 4096, 1024, gn, npgs, mpg, bpg, npt);
    }
    // gemm2: M x 1024, K=4096, GN=1 (A=u streamed once per XCD m-slice, B L3-hot)
    {
      int tm = Mc >> 8, tn = 4, gn = 0;
      int tiles = tm * tn;
      int grid = tiles < 256 ? tiles : 256;
      int npt = tiles / grid, bpg = grid >> 3;
      int npgs = ilog2(tn >> gn);
      int mpg = tm >> (3 - gn);
      gemm256<0><<<dim3(grid), blk2, 0, stream>>>(u, w2T, b2, hch, ych,
                                                  Mc, 1024, 4096, gn, npgs, mpg, bpg, npt);
    }
  }
  ln_rows<<<dim3(16384, 1, 1), blk, 0, stream>>>(y, g2, be2, out);
}

// Round 6
// 549.255 us; speedup vs baseline: 1.0425x; 1.0425x over previous
//
#include <hip/hip_runtime.h>
#include <math.h>
#include <stdint.h>

#define DI __device__ __forceinline__
typedef unsigned short u16;
typedef unsigned int   u32;
typedef unsigned long long u64;

typedef __attribute__((ext_vector_type(4))) float f32x4;
typedef __attribute__((ext_vector_type(8))) short bf16x8;

DI float bf2f(u16 v){ return __uint_as_float(((u32)v) << 16); }
DI u16 f2bf(float f){ u32 u = __float_as_uint(f); return (u16)((u + 0x7FFFu + ((u >> 16) & 1u)) >> 16); }
DI u32 pack2(float re, float im){ return (u32)f2bf(re) | ((u32)f2bf(im) << 16); }

// tanh-form GELU: v*sigmoid(2z), z = sqrt(2/pi)(v+0.044715v^3). Max |err| vs exact
// erf-GELU ~5e-4 (budget 0.11). ~9 VALU incl one v_exp. z clamped: exp overflow guard.
DI float gelu_fast(float v){
  float t = v * v;
  float z = v * fmaf(0.0356774081f, t, 0.7978845608f);
  z = fminf(z, 15.0f);
  float e = __expf(2.0f * z);
  return v * e * __frcp_rn(1.0f + e);
}

// ---------------- tiled transposes (coalesced both sides) ----------------
__global__ __launch_bounds__(256) void transpose_u32(const u32* __restrict__ in, u32* __restrict__ out, int R, int C){
  __shared__ u32 tile[64][65];
  int t = threadIdx.x;
  int c = t & 63, r0 = t >> 6;
  size_t bofs = (size_t)blockIdx.z * (size_t)R * (size_t)C;
  const u32* ib = in  + bofs + (size_t)(blockIdx.y * 64) * C + blockIdx.x * 64;
  u32*       ob = out + bofs + (size_t)(blockIdx.x * 64) * R + blockIdx.y * 64;
  #pragma unroll
  for (int i = 0; i < 16; i++){ int r = r0 + i * 4; tile[r][c] = ib[(size_t)r * C + c]; }
  __syncthreads();
  #pragma unroll
  for (int i = 0; i < 16; i++){ int r = r0 + i * 4; ob[(size_t)r * R + c] = tile[c][r]; }
}

// both weight transposes in ONE launch (z=0: w1 1024x4096; z=1: w2 4096x1024).
// fp32 in -> bf16 transposed out (weights: KxN -> NxK bf16). grid (64,16,2);
// z=1 swaps block coords so (16,64) coverage comes from the same grid.
__global__ __launch_bounds__(256) void transpose_w(const float* __restrict__ w1, u16* __restrict__ w1T,
                                                   const float* __restrict__ w2, u16* __restrict__ w2T){
  __shared__ u16 tile[64][65];
  int t = threadIdx.x;
  int c = t & 63, r0 = t >> 6;
  const float* in; u16* out; int R, C, bx, by;
  if (blockIdx.z == 0){ in = w1; out = w1T; R = 1024; C = 4096; bx = blockIdx.x; by = blockIdx.y; }
  else                { in = w2; out = w2T; R = 4096; C = 1024; bx = blockIdx.y; by = blockIdx.x; }
  const float* ib = in  + (size_t)(by * 64) * C + bx * 64;
  u16*         ob = out + (size_t)(bx * 64) * R + by * 64;
  #pragma unroll
  for (int i = 0; i < 16; i++){ int r = r0 + i * 4; tile[r][c] = f2bf(ib[(size_t)r * C + c]); }
  __syncthreads();
  #pragma unroll
  for (int i = 0; i < 16; i++){ int r = r0 + i * 4; ob[(size_t)r * R + c] = tile[c][r]; }
}

// ---------------- radix-4 Stockham FFT in LDS (float2 AoS, b64 DS ops) ----------------
template<int LOGN>
DI float2* fft_r4(float2* s, float2* d, int t){
  const int Q = 1 << (LOGN - 2);
  #pragma unroll
  for (int st = 0; st < (LOGN >> 1); ++st){
    const int m = 1 << (2 * st);
    const float ang = -6.28318530717958647692f * (float)m / (float)(1 << LOGN);
    #pragma unroll
    for (int j0 = 0; j0 < Q; j0 += 256){
      int j = j0 + t;
      int p = j >> (2 * st);
      int q = j & (m - 1);
      int o = q + (p << (2 * st + 2));
      float2 a0 = s[j], a1 = s[j + Q], a2 = s[j + 2 * Q], a3 = s[j + 3 * Q];
      float s0r = a0.x + a2.x, s0i = a0.y + a2.y, d0r = a0.x - a2.x, d0i = a0.y - a2.y;
      float s1r = a1.x + a3.x, s1i = a1.y + a3.y, d1r = a1.x - a3.x, d1i = a1.y - a3.y;
      float sn, cs; __sincosf(ang * (float)p, &sn, &cs);
      float t2r = cs * cs - sn * sn, t2i = 2.f * cs * sn;
      float t3r = t2r * cs - t2i * sn, t3i = t2r * sn + t2i * cs;
      float e1r = d0r + d1i, e1i = d0i - d1r;
      float e2r = s0r - s1r, e2i = s0i - s1i;
      float e3r = d0r - d1i, e3i = d0i + d1r;
      d[o]         = make_float2(s0r + s1r, s0i + s1i);
      d[o + m]     = make_float2(cs * e1r - sn * e1i,  cs * e1i + sn * e1r);
      d[o + 2 * m] = make_float2(t2r * e2r - t2i * e2i, t2r * e2i + t2i * e2r);
      d[o + 3 * m] = make_float2(t3r * e3r - t3i * e3i, t3r * e3i + t3i * e3r);
    }
    __syncthreads();
    float2* tp = s; s = d; d = tp;
  }
  return s;
}

// K1: packed real FFT over seq. Block g handles rows 2g,2g+1 of xT as z=xa+i*xb.
__global__ __launch_bounds__(256) void fft_seq(const float* __restrict__ xT, u32* __restrict__ ZT2,
                                               float* __restrict__ Zny){
  __shared__ float2 A[4096], Bb[4096];  // 64 KB
  int t = threadIdx.x, g = blockIdx.x;  // g in [0,2048)
  const float* r0 = xT + (size_t)(2 * g) * 4096;
  #pragma unroll
  for (int i = 0; i < 4; i++){
    int idx = i * 1024 + t * 4;
    float4 va = *(const float4*)(r0 + idx);
    float4 vb = *(const float4*)(r0 + 4096 + idx);
    A[idx + 0] = make_float2(va.x, vb.x);
    A[idx + 1] = make_float2(va.y, vb.y);
    A[idx + 2] = make_float2(va.z, vb.z);
    A[idx + 3] = make_float2(va.w, vb.w);
  }
  __syncthreads();
  float2* R = fft_r4<12>(A, Bb, t);
  size_t ob0 = (size_t)(2 * g) * 2048;
  #pragma unroll
  for (int i = 0; i < 2; i++){
    int k0 = i * 1024 + t * 4;
    u32 wa[4], wb[4];
    #pragma unroll
    for (int kk = 0; kk < 4; kk++){
      int k = k0 + kk, m = (4096 - k) & 4095;
      float2 zk = R[k], zm = R[m];
      wa[kk] = pack2(0.5f * (zk.x + zm.x), 0.5f * (zk.y - zm.y));   // Xa = (Z+conj(Zm))/2
      wb[kk] = pack2(0.5f * (zk.y + zm.y), 0.5f * (zm.x - zk.x));   // Xb = -i(Z-conj(Zm))/2
    }
    *(uint4*)(ZT2 + ob0 + k0)        = make_uint4(wa[0], wa[1], wa[2], wa[3]);
    *(uint4*)(ZT2 + ob0 + 2048 + k0) = make_uint4(wb[0], wb[1], wb[2], wb[3]);
  }
  if (t == 0){ float2 z = R[2048]; Zny[2 * g] = z.x; Zny[2 * g + 1] = z.y; }
}

DI void block_stats4(float a1, float a2, float b1, float b2, int t,
                     float& mA, float& iA, float& mB, float& iB){
  __shared__ float sh[4][4];
  #pragma unroll
  for (int o = 32; o > 0; o >>= 1){
    a1 += __shfl_down(a1, o); a2 += __shfl_down(a2, o);
    b1 += __shfl_down(b1, o); b2 += __shfl_down(b2, o);
  }
  if ((t & 63) == 0){ int w = t >> 6; sh[w][0] = a1; sh[w][1] = a2; sh[w][2] = b1; sh[w][3] = b2; }
  __syncthreads();
  float SA = sh[0][0] + sh[1][0] + sh[2][0] + sh[3][0];
  float QA = sh[0][1] + sh[1][1] + sh[2][1] + sh[3][1];
  float SB = sh[0][2] + sh[1][2] + sh[2][2] + sh[3][2];
  float QB = sh[0][3] + sh[1][3] + sh[2][3] + sh[3][3];
  mA = SA * (1.f / 1024.f); iA = rsqrtf(QA * (1.f / 1024.f) - mA * mA + 1e-5f);
  mB = SB * (1.f / 1024.f); iB = rsqrtf(QB * (1.f / 1024.f) - mB * mB + 1e-5f);
}

// K2: hidden FFT for k=0..2048 (Hermitian mirror gives row 4096-k), +x residual, LN1 -> h (bf16)
__global__ __launch_bounds__(256) void fft_hid_ln(const u32* __restrict__ Z2, const float* __restrict__ Zny,
    const float* __restrict__ x, const float* __restrict__ g1, const float* __restrict__ be1,
    u16* __restrict__ h){
  __shared__ float2 A[1024], Bb[1024];  // 16 KB
  int t = threadIdx.x, id = blockIdx.x;
  int b = id / 2049, k = id - b * 2049;
  int idx = t * 4;
  if (k == 2048){
    float4 v = *(const float4*)(Zny + b * 1024 + idx);
    A[idx + 0] = make_float2(v.x, 0.f); A[idx + 1] = make_float2(v.y, 0.f);
    A[idx + 2] = make_float2(v.z, 0.f); A[idx + 3] = make_float2(v.w, 0.f);
  } else {
    uint4 zv = *(const uint4*)(Z2 + ((size_t)b * 2048 + k) * 1024 + idx);
    A[idx + 0] = make_float2(bf2f((u16)(zv.x & 0xffffu)), bf2f((u16)(zv.x >> 16)));
    A[idx + 1] = make_float2(bf2f((u16)(zv.y & 0xffffu)), bf2f((u16)(zv.y >> 16)));
    A[idx + 2] = make_float2(bf2f((u16)(zv.z & 0xffffu)), bf2f((u16)(zv.z >> 16)));
    A[idx + 3] = make_float2(bf2f((u16)(zv.w & 0xffffu)), bf2f((u16)(zv.w >> 16)));
  }
  __syncthreads();
  float2* R = fft_r4<10>(A, Bb, t);
  int rowA = b * 4096 + k;
  bool two = (k >= 1) && (k <= 2047);
  int rowB = b * 4096 + (4096 - k);
  float4 xa = *(const float4*)(x + (size_t)rowA * 1024 + idx);
  float vA0 = R[idx + 0].x + xa.x, vA1 = R[idx + 1].x + xa.y;
  float vA2 = R[idx + 2].x + xa.z, vA3 = R[idx + 3].x + xa.w;
  float vB0 = 0.f, vB1 = 0.f, vB2 = 0.f, vB3 = 0.f;
  if (two){
    float4 xb = *(const float4*)(x + (size_t)rowB * 1024 + idx);
    vB0 = R[(1024 - (idx + 0)) & 1023].x + xb.x;   // Re(Y[4096-k,m]) = Re(Y[k,(1024-m)&1023])
    vB1 = R[(1024 - (idx + 1)) & 1023].x + xb.y;
    vB2 = R[(1024 - (idx + 2)) & 1023].x + xb.z;
    vB3 = R[(1024 - (idx + 3)) & 1023].x + xb.w;
  }
  float mA, iA, mB, iB;
  block_stats4(vA0 + vA1 + vA2 + vA3, vA0 * vA0 + vA1 * vA1 + vA2 * vA2 + vA3 * vA3,
               vB0 + vB1 + vB2 + vB3, vB0 * vB0 + vB1 * vB1 + vB2 * vB2 + vB3 * vB3,
               t, mA, iA, mB, iB);
  float4 gv = *(const float4*)(g1 + idx);
  float4 bv = *(const float4*)(be1 + idx);
  ushort4 oA;
  oA.x = f2bf((vA0 - mA) * iA * gv.x + bv.x);
  oA.y = f2bf((vA1 - mA) * iA * gv.y + bv.y);
  oA.z = f2bf((vA2 - mA) * iA * gv.z + bv.z);
  oA.w = f2bf((vA3 - mA) * iA * gv.w + bv.w);
  *(ushort4*)(h + (size_t)rowA * 1024 + idx) = oA;
  if (two){
    ushort4 oB;
    oB.x = f2bf((vB0 - mB) * iB * gv.x + bv.x);
    oB.y = f2bf((vB1 - mB) * iB * gv.y + bv.y);
    oB.z = f2bf((vB2 - mB) * iB * gv.z + bv.z);
    oB.w = f2bf((vB3 - mB) * iB * gv.w + bv.w);
    *(ushort4*)(h + (size_t)rowB * 1024 + idx) = oB;
  }
}

// K3: final LayerNorm on y rows (bf16) -> out (fp32)
__global__ __launch_bounds__(256) void ln_rows(const u16* __restrict__ yv, const float* __restrict__ g,
    const float* __restrict__ be, float* __restrict__ o){
  int t = threadIdx.x;
  size_t base = (size_t)blockIdx.x * 1024;
  int idx = t * 4;
  ushort4 v4 = *(const ushort4*)(yv + base + idx);
  float v0 = bf2f(v4.x), v1 = bf2f(v4.y), v2 = bf2f(v4.z), v3 = bf2f(v4.w);
  float mA, iA, mB, iB;
  block_stats4(v0 + v1 + v2 + v3, v0 * v0 + v1 * v1 + v2 * v2 + v3 * v3, 0.f, 0.f, t, mA, iA, mB, iB);
  float4 gv = *(const float4*)(g + idx);
  float4 bv = *(const float4*)(be + idx);
  float4 ov;
  ov.x = (v0 - mA) * iA * gv.x + bv.x;
  ov.y = (v1 - mA) * iA * gv.y + bv.y;
  ov.z = (v2 - mA) * iA * gv.z + bv.z;
  ov.w = (v3 - mA) * iA * gv.w + bv.w;
  *(float4*)(o + base + idx) = ov;
}

// ======================= persistent 256x256 8-phase bf16 GEMM (r4 state, best) ==========
// C = epi(A @ B^T + bias); A: MxK bf16, Bm: NxK bf16. 512 thr = 8 waves (2M x 4N),
// per-wave 128x64 out, acc[8][4] 16x16x32 MFMA. BK=64 in two 32-k slabs; LDS 128 KiB.
// Verified signature: 184.4 us, MfmaUtil 32%, SQ_LDS_BANK_CONFLICT 0, VGPR 128.
// (r5's 32x32x16 variant REGRESSED: +1cyc/b128 LDS conflict, -9% wall. Do not retry.)
// Schedule: reads hoisted (P0: all ks0, P1: all ks1); stage 1 unit per phase; counted
// vmcnt(6) once/K-tile; lgkmcnt(0) end of P1 guards ks1 overwrite; T2 swizzle both-sides.
typedef const __attribute__((address_space(1))) void* as1cp;
typedef __attribute__((address_space(3))) void* as3p;
DI void async_copy16(const void* g, void* l){
  __builtin_amdgcn_global_load_lds((as1cp)(u64)g, (as3p)(u32)(u64)l, 16, 0, 0);
}
DI void bar(){
  asm volatile("" ::: "memory");
  __builtin_amdgcn_s_barrier();
  asm volatile("" ::: "memory");
}

template<int DOGELU>
__global__ __launch_bounds__(512, 2) void gemm256(const u16* __restrict__ A, const u16* __restrict__ Bm,
    const float* __restrict__ bias, const u16* __restrict__ resid, u16* __restrict__ C,
    int M, int N, int K, int gn_shift, int npg_shift, int mpg, int bpg, int npt)
{
  __shared__ u16 sA[2][2][8192];   // [buf][ks][256 rows x 32 k]
  __shared__ u16 sB[2][2][8192];
  int t = threadIdx.x, wv = t >> 6, ln = t & 63;

  int bid = blockIdx.x;
  int c8 = bid & 7, j0 = bid >> 3;
  int ng = c8 & ((1 << gn_shift) - 1);
  int mg = c8 >> gn_shift;
  int npg_m1 = (1 << npg_shift) - 1;

  int wm = wv >> 2, wn = wv & 3;       // wave -> (m-half, n-quarter) of the 256x256 tile
  int lt = ln & 15;
  int cs = (((ln >> 4) ^ ((ln >> 1) & 3)) << 3);      // swizzled k-chunk (u16 units)
  int arow = (wm * 128 + lt) * 32 + cs;
  int brow = (wn * 64 + lt) * 32 + cs;
  int srow = wv * 32 + (ln >> 2);
  int gch  = ((ln & 3) ^ ((srow >> 1) & 3)) << 3;     // inverse swizzle on global source
  int ldof = wv * 1024 + ln * 8;
  int NT = K >> 6;

  #define STAGE(g0, g1, kc, unit) do{ \
    async_copy16((g0) + (kc), (unit) + ldof); \
    async_copy16((g1) + (kc), (unit) + 512 + ldof); }while(0)
  #define PROLOGUE() do{ \
    STAGE(gA0, gA1, 0,  &sA[0][0][0]); \
    STAGE(gB0, gB1, 0,  &sB[0][0][0]); \
    STAGE(gA0, gA1, 32, &sA[0][1][0]); \
    STAGE(gB0, gB1, 32, &sB[0][1][0]); \
    STAGE(gA0, gA1, 64, &sA[1][0][0]); \
    STAGE(gB0, gB1, 64, &sB[1][0][0]); \
    STAGE(gA0, gA1, 96, &sA[1][1][0]); }while(0)

  // tile 0 pointers + initial prologue
  int jt = j0;
  int n0 = (((ng << npg_shift) + (jt & npg_m1)) << 8);
  int m0 = ((mg * mpg + (jt >> npg_shift)) << 8);
  const u16* gA0 = A  + (size_t)(m0 + srow) * K + gch;
  const u16* gA1 = gA0 + (size_t)16 * K;
  const u16* gB0 = Bm + (size_t)(n0 + srow) * K + gch;
  const u16* gB1 = gB0 + (size_t)16 * K;
  PROLOGUE();
  asm volatile("s_waitcnt vmcnt(6)" ::: "memory");   // tile0 resident; tile1 in flight
  bar();

  for (int s = 0; s < npt; ++s){
    f32x4 acc[8][4];
    #pragma unroll
    for (int mf = 0; mf < 8; mf++)
      #pragma unroll
      for (int nf = 0; nf < 4; nf++) acc[mf][nf] = (f32x4){0.f, 0.f, 0.f, 0.f};

    for (int kt = 0; kt < NT; ++kt){
      int buf = kt & 1;
      u16* a0s = &sA[buf][0][0];
      u16* a1s = &sA[buf][1][0];
      u16* b0s = &sB[buf][0][0];
      u16* b1s = &sB[buf][1][0];
      u16* bn1 = &sB[buf ^ 1][1][0];     // B(kt+1)-ks1 dest (other buf)
      bool st1 = (kt + 1) < NT;
      bool st2 = (kt + 2) < NT;
      int kb1 = (kt + 1) << 6, kb2 = (kt + 2) << 6;
      bf16x8 af1[8], af2[8], b1r[4], b2r[4];

      // ---- P0: rd ALL ks0 frags; stage B(kt+1)ks1; MFMA (ks0, nf0-1)
      #pragma unroll
      for (int mf = 0; mf < 8; mf++) af1[mf] = *(const bf16x8*)(a0s + arow + mf * 512);
      #pragma unroll
      for (int nf = 0; nf < 4; nf++) b1r[nf] = *(const bf16x8*)(b0s + brow + nf * 512);
      if (st1) STAGE(gB0, gB1, kb1 + 32, bn1);
      bar();
      __builtin_amdgcn_s_setprio(1);
      #pragma unroll
      for (int mf = 0; mf < 8; mf++){
        acc[mf][0] = __builtin_amdgcn_mfma_f32_16x16x32_bf16(af1[mf], b1r[0], acc[mf][0], 0, 0, 0);
        acc[mf][1] = __builtin_amdgcn_mfma_f32_16x16x32_bf16(af1[mf], b1r[1], acc[mf][1], 0, 0, 0);
      }
      __builtin_amdgcn_s_setprio(0);
      bar();

      // ---- P1: rd ALL ks1 frags; stage A(kt+2)ks0; MFMA (ks0, nf2-3); lgkm drain
      #pragma unroll
      for (int mf = 0; mf < 8; mf++) af2[mf] = *(const bf16x8*)(a1s + arow + mf * 512);
      #pragma unroll
      for (int nf = 0; nf < 4; nf++) b2r[nf] = *(const bf16x8*)(b1s + brow + nf * 512);
      if (st2) STAGE(gA0, gA1, kb2, a0s);
      bar();
      __builtin_amdgcn_s_setprio(1);
      #pragma unroll
      for (int mf = 0; mf < 8; mf++){
        acc[mf][2] = __builtin_amdgcn_mfma_f32_16x16x32_bf16(af1[mf], b1r[2], acc[mf][2], 0, 0, 0);
        acc[mf][3] = __builtin_amdgcn_mfma_f32_16x16x32_bf16(af1[mf], b1r[3], acc[mf][3], 0, 0, 0);
      }
      __builtin_amdgcn_s_setprio(0);
      asm volatile("s_waitcnt lgkmcnt(0)" ::: "memory");  // all ks1 reads retired pre-overwrite
      bar();

      // ---- P2: stage B(kt+2)ks0; MFMA (ks1, nf0-1) -- frags already in regs
      if (st2) STAGE(gB0, gB1, kb2, b0s);
      bar();
      __builtin_amdgcn_s_setprio(1);
      #pragma unroll
      for (int mf = 0; mf < 8; mf++){
        acc[mf][0] = __builtin_amdgcn_mfma_f32_16x16x32_bf16(af2[mf], b2r[0], acc[mf][0], 0, 0, 0);
        acc[mf][1] = __builtin_amdgcn_mfma_f32_16x16x32_bf16(af2[mf], b2r[1], acc[mf][1], 0, 0, 0);
      }
      __builtin_amdgcn_s_setprio(0);
      bar();

      // ---- P3: stage A(kt+2)ks1; MFMA (ks1, nf2-3); boundary vmcnt
      if (st2) STAGE(gA0, gA1, kb2 + 32, a1s);
      bar();
      __builtin_amdgcn_s_setprio(1);
      #pragma unroll
      for (int mf = 0; mf < 8; mf++){
        acc[mf][2] = __builtin_amdgcn_mfma_f32_16x16x32_bf16(af2[mf], b2r[2], acc[mf][2], 0, 0, 0);
        acc[mf][3] = __builtin_amdgcn_mfma_f32_16x16x32_bf16(af2[mf], b2r[3], acc[mf][3], 0, 0, 0);
      }
      __builtin_amdgcn_s_setprio(0);
      if (st2) asm volatile("s_waitcnt vmcnt(6)" ::: "memory");  // tile kt+1 landed; 3 units in flight
      else     asm volatile("s_waitcnt vmcnt(0)" ::: "memory");  // tail: drain before LDS reuse
      bar();
    }

    // prestage tile s+1 BEFORE epilogue: staging latency hides under epilogue VALU.
    int em0 = m0, en0 = n0;
    if (s + 1 < npt){
      jt = j0 + (s + 1) * bpg;
      n0 = (((ng << npg_shift) + (jt & npg_m1)) << 8);
      m0 = ((mg * mpg + (jt >> npg_shift)) << 8);
      gA0 = A  + (size_t)(m0 + srow) * K + gch;
      gA1 = gA0 + (size_t)16 * K;
      gB0 = Bm + (size_t)(n0 + srow) * K + gch;
      gB1 = gB0 + (size_t)16 * K;
      PROLOGUE();
    }

    // epilogue: D col = lane&15, row = (lane>>4)*4 + reg  [m89-verified mapping]
    int colq = lt, rq = ln >> 4;
    #pragma unroll
    for (int mf = 0; mf < 8; mf++){
      int mr = em0 + wm * 128 + mf * 16 + rq * 4;
      #pragma unroll
      for (int nf = 0; nf < 4; nf++){
        int col = en0 + wn * 64 + nf * 16 + colq;
        float bv = bias[col];
        #pragma unroll
        for (int i = 0; i < 4; i++){
          float v = acc[mf][nf][i] + bv;
          if (DOGELU){
            v = gelu_fast(v);
          } else {
            v += bf2f(resid[(size_t)(mr + i) * N + col]);
          }
          C[(size_t)(mr + i) * N + col] = f2bf(v);
        }
      }
    }

    if (s + 1 < npt){
      // in-order vmcnt retirement: waiting to <=6 retires all 14 prestage instrs
      // (older than the epilogue stores); the 6 left in flight are newest stores.
      asm volatile("s_waitcnt vmcnt(6)" ::: "memory");
      bar();
    }
  }
  #undef PROLOGUE
  #undef STAGE
}

// ---------------- orchestration ----------------
// B=4, S=4096, H=1024, fp32 I/O. ws >= 209 MiB proven (round-3 nch=1 FETCH signature).
static inline int ilog2(int v){ int s = 0; while ((1 << s) < v) ++s; return s; }

extern "C" void kernel_launch(void* const* d_in, const int* in_sizes, int n_in,
                              void* d_out, int out_size, void* d_ws, size_t ws_size,
                              hipStream_t stream){
  const float* x   = (const float*)d_in[0];
  const float* w1  = (const float*)d_in[1];
  const float* b1  = (const float*)d_in[2];
  const float* w2  = (const float*)d_in[3];
  const float* b2  = (const float*)d_in[4];
  const float* g1  = (const float*)d_in[5];
  const float* be1 = (const float*)d_in[6];
  const float* g2  = (const float*)d_in[7];
  const float* be2 = (const float*)d_in[8];
  float* out = (float*)d_out;
  char* ws = (char*)d_ws;
  const size_t MB = (size_t)1 << 20;
  float* xT  = (float*)(ws);
  u32*  ZT2  = (u32*)(ws + 64 * MB);
  float* Zny = (float*)(ws + 96 * MB);
  u32*  Z2   = (u32*)(ws);
  u16*  h    = (u16*)(ws + 32 * MB);
  u16*  w1T  = (u16*)(ws + 64 * MB);
  u16*  w2T  = (u16*)(ws + 72 * MB);
  u16*  u    = (u16*)(ws + 80 * MB);
  u16*  y    = (u16*)(ws);
  dim3 blk(256, 1, 1);
  dim3 blk2(512, 1, 1);

  // mixing: seq FFT (packed real pairs) -> Hermitian half -> hidden FFT (+x, LN1)
  transpose_u32<<<dim3(16, 64, 4), blk, 0, stream>>>((const u32*)x, (u32*)xT, 4096, 1024);
  fft_seq      <<<dim3(2048, 1, 1), blk, 0, stream>>>(xT, ZT2, Zny);
  transpose_u32<<<dim3(32, 16, 4), blk, 0, stream>>>(ZT2, Z2, 1024, 2048);
  fft_hid_ln   <<<dim3(4 * 2049, 1, 1), blk, 0, stream>>>(Z2, Zny, x, g1, be1, h);

  // FFN (both weight transposes in one launch)
  transpose_w<<<dim3(64, 16, 2), blk, 0, stream>>>(w1, w1T, w2, w2T);
  int nch = (ws_size >= (size_t)209 * MB) ? 1 : (ws_size >= (size_t)145 * MB) ? 2 : 4;
  int Mc = 16384 / nch;
  for (int ch = 0; ch < nch; ++ch){
    const u16* hch = h + (size_t)ch * Mc * 1024;
    u16* ych = y + (size_t)ch * Mc * 1024;
    // gemm1: M x 4096, K=1024, GN=4 n-groups (B-slice 2MB L2-locked)
    {
      int tm = Mc >> 8, tn = 16, gn = 2;
      int tiles = tm * tn;
      int grid = tiles < 256 ? tiles : 256;
      int npt = tiles / grid, bpg = grid >> 3;
      int npgs = ilog2(tn >> gn);
      int mpg = tm >> (3 - gn);
      gemm256<1><<<dim3(grid), blk2, 0, stream>>>(hch, w1T, b1, (const u16*)nullptr, u,
                                                  Mc, 4096, 1024, gn, npgs, mpg, bpg, npt);
    }
    // gemm2: M x 1024, K=4096, GN=1 (A=u streamed once per XCD m-slice, B L3-hot)
    {
      int tm = Mc >> 8, tn = 4, gn = 0;
      int tiles = tm * tn;
      int grid = tiles < 256 ? tiles : 256;
      int npt = tiles / grid, bpg = grid >> 3;
      int npgs = ilog2(tn >> gn);
      int mpg = tm >> (3 - gn);
      gemm256<0><<<dim3(grid), blk2, 0, stream>>>(u, w2T, b2, hch, ych,
                                                  Mc, 1024, 4096, gn, npgs, mpg, bpg, npt);
    }
  }
  ln_rows<<<dim3(16384, 1, 1), blk, 0, stream>>>(y, g2, be2, out);
}

// Round 7
// 538.448 us; speedup vs baseline: 1.0634x; 1.0201x over previous
//
#include <hip/hip_runtime.h>
#include <math.h>
#include <stdint.h>

#define DI __device__ __forceinline__
typedef unsigned short u16;
typedef unsigned int   u32;
typedef unsigned long long u64;

typedef __attribute__((ext_vector_type(4))) float f32x4;
typedef __attribute__((ext_vector_type(8))) short bf16x8;

DI float bf2f(u16 v){ return __uint_as_float(((u32)v) << 16); }
DI u16 f2bf(float f){ u32 u = __float_as_uint(f); return (u16)((u + 0x7FFFu + ((u >> 16) & 1u)) >> 16); }
DI u32 pack2(float re, float im){ return (u32)f2bf(re) | ((u32)f2bf(im) << 16); }

// tanh-form GELU: v*sigmoid(2z), z = sqrt(2/pi)(v+0.044715v^3). Max |err| vs exact
// erf-GELU ~5e-4 (budget 0.11). ~9 VALU incl one v_exp. z clamped: exp overflow guard.
DI float gelu_fast(float v){
  float t = v * v;
  float z = v * fmaf(0.0356774081f, t, 0.7978845608f);
  z = fminf(z, 15.0f);
  float e = __expf(2.0f * z);
  return v * e * __frcp_rn(1.0f + e);
}

// ---------------- tiled transposes (coalesced both sides) ----------------
__global__ __launch_bounds__(256) void transpose_u32(const u32* __restrict__ in, u32* __restrict__ out, int R, int C){
  __shared__ u32 tile[64][65];
  int t = threadIdx.x;
  int c = t & 63, r0 = t >> 6;
  size_t bofs = (size_t)blockIdx.z * (size_t)R * (size_t)C;
  const u32* ib = in  + bofs + (size_t)(blockIdx.y * 64) * C + blockIdx.x * 64;
  u32*       ob = out + bofs + (size_t)(blockIdx.x * 64) * R + blockIdx.y * 64;
  #pragma unroll
  for (int i = 0; i < 16; i++){ int r = r0 + i * 4; tile[r][c] = ib[(size_t)r * C + c]; }
  __syncthreads();
  #pragma unroll
  for (int i = 0; i < 16; i++){ int r = r0 + i * 4; ob[(size_t)r * R + c] = tile[c][r]; }
}

// both weight transposes in ONE launch (z=0: w1 1024x4096; z=1: w2 4096x1024).
// fp32 in -> bf16 transposed out (weights: KxN -> NxK bf16). grid (64,16,2);
// z=1 swaps block coords so (16,64) coverage comes from the same grid.
__global__ __launch_bounds__(256) void transpose_w(const float* __restrict__ w1, u16* __restrict__ w1T,
                                                   const float* __restrict__ w2, u16* __restrict__ w2T){
  __shared__ u16 tile[64][65];
  int t = threadIdx.x;
  int c = t & 63, r0 = t >> 6;
  const float* in; u16* out; int R, C, bx, by;
  if (blockIdx.z == 0){ in = w1; out = w1T; R = 1024; C = 4096; bx = blockIdx.x; by = blockIdx.y; }
  else                { in = w2; out = w2T; R = 4096; C = 1024; bx = blockIdx.y; by = blockIdx.x; }
  const float* ib = in  + (size_t)(by * 64) * C + bx * 64;
  u16*         ob = out + (size_t)(bx * 64) * R + by * 64;
  #pragma unroll
  for (int i = 0; i < 16; i++){ int r = r0 + i * 4; tile[r][c] = f2bf(ib[(size_t)r * C + c]); }
  __syncthreads();
  #pragma unroll
  for (int i = 0; i < 16; i++){ int r = r0 + i * 4; ob[(size_t)r * R + c] = tile[c][r]; }
}

// ---------------- radix-4 Stockham FFT in LDS (float2 AoS, b64 DS ops) ----------------
template<int LOGN>
DI float2* fft_r4(float2* s, float2* d, int t){
  const int Q = 1 << (LOGN - 2);
  #pragma unroll
  for (int st = 0; st < (LOGN >> 1); ++st){
    const int m = 1 << (2 * st);
    const float ang = -6.28318530717958647692f * (float)m / (float)(1 << LOGN);
    #pragma unroll
    for (int j0 = 0; j0 < Q; j0 += 256){
      int j = j0 + t;
      int p = j >> (2 * st);
      int q = j & (m - 1);
      int o = q + (p << (2 * st + 2));
      float2 a0 = s[j], a1 = s[j + Q], a2 = s[j + 2 * Q], a3 = s[j + 3 * Q];
      float s0r = a0.x + a2.x, s0i = a0.y + a2.y, d0r = a0.x - a2.x, d0i = a0.y - a2.y;
      float s1r = a1.x + a3.x, s1i = a1.y + a3.y, d1r = a1.x - a3.x, d1i = a1.y - a3.y;
      float sn, cs; __sincosf(ang * (float)p, &sn, &cs);
      float t2r = cs * cs - sn * sn, t2i = 2.f * cs * sn;
      float t3r = t2r * cs - t2i * sn, t3i = t2r * sn + t2i * cs;
      float e1r = d0r + d1i, e1i = d0i - d1r;
      float e2r = s0r - s1r, e2i = s0i - s1i;
      float e3r = d0r - d1i, e3i = d0i + d1r;
      d[o]         = make_float2(s0r + s1r, s0i + s1i);
      d[o + m]     = make_float2(cs * e1r - sn * e1i,  cs * e1i + sn * e1r);
      d[o + 2 * m] = make_float2(t2r * e2r - t2i * e2i, t2r * e2i + t2i * e2r);
      d[o + 3 * m] = make_float2(t3r * e3r - t3i * e3i, t3r * e3i + t3i * e3r);
    }
    __syncthreads();
    float2* tp = s; s = d; d = tp;
  }
  return s;
}

// K1: packed real FFT over seq. Block g handles rows 2g,2g+1 of xT as z=xa+i*xb.
__global__ __launch_bounds__(256) void fft_seq(const float* __restrict__ xT, u32* __restrict__ ZT2,
                                               float* __restrict__ Zny){
  __shared__ float2 A[4096], Bb[4096];  // 64 KB
  int t = threadIdx.x, g = blockIdx.x;  // g in [0,2048)
  const float* r0 = xT + (size_t)(2 * g) * 4096;
  #pragma unroll
  for (int i = 0; i < 4; i++){
    int idx = i * 1024 + t * 4;
    float4 va = *(const float4*)(r0 + idx);
    float4 vb = *(const float4*)(r0 + 4096 + idx);
    A[idx + 0] = make_float2(va.x, vb.x);
    A[idx + 1] = make_float2(va.y, vb.y);
    A[idx + 2] = make_float2(va.z, vb.z);
    A[idx + 3] = make_float2(va.w, vb.w);
  }
  __syncthreads();
  float2* R = fft_r4<12>(A, Bb, t);
  size_t ob0 = (size_t)(2 * g) * 2048;
  #pragma unroll
  for (int i = 0; i < 2; i++){
    int k0 = i * 1024 + t * 4;
    u32 wa[4], wb[4];
    #pragma unroll
    for (int kk = 0; kk < 4; kk++){
      int k = k0 + kk, m = (4096 - k) & 4095;
      float2 zk = R[k], zm = R[m];
      wa[kk] = pack2(0.5f * (zk.x + zm.x), 0.5f * (zk.y - zm.y));   // Xa = (Z+conj(Zm))/2
      wb[kk] = pack2(0.5f * (zk.y + zm.y), 0.5f * (zm.x - zk.x));   // Xb = -i(Z-conj(Zm))/2
    }
    *(uint4*)(ZT2 + ob0 + k0)        = make_uint4(wa[0], wa[1], wa[2], wa[3]);
    *(uint4*)(ZT2 + ob0 + 2048 + k0) = make_uint4(wb[0], wb[1], wb[2], wb[3]);
  }
  if (t == 0){ float2 z = R[2048]; Zny[2 * g] = z.x; Zny[2 * g + 1] = z.y; }
}

DI void block_stats4(float a1, float a2, float b1, float b2, int t,
                     float& mA, float& iA, float& mB, float& iB){
  __shared__ float sh[4][4];
  #pragma unroll
  for (int o = 32; o > 0; o >>= 1){
    a1 += __shfl_down(a1, o); a2 += __shfl_down(a2, o);
    b1 += __shfl_down(b1, o); b2 += __shfl_down(b2, o);
  }
  if ((t & 63) == 0){ int w = t >> 6; sh[w][0] = a1; sh[w][1] = a2; sh[w][2] = b1; sh[w][3] = b2; }
  __syncthreads();
  float SA = sh[0][0] + sh[1][0] + sh[2][0] + sh[3][0];
  float QA = sh[0][1] + sh[1][1] + sh[2][1] + sh[3][1];
  float SB = sh[0][2] + sh[1][2] + sh[2][2] + sh[3][2];
  float QB = sh[0][3] + sh[1][3] + sh[2][3] + sh[3][3];
  mA = SA * (1.f / 1024.f); iA = rsqrtf(QA * (1.f / 1024.f) - mA * mA + 1e-5f);
  mB = SB * (1.f / 1024.f); iB = rsqrtf(QB * (1.f / 1024.f) - mB * mB + 1e-5f);
}

// K2: hidden FFT for k=0..2048 (Hermitian mirror gives row 4096-k), +x residual, LN1 -> h (bf16)
__global__ __launch_bounds__(256) void fft_hid_ln(const u32* __restrict__ Z2, const float* __restrict__ Zny,
    const float* __restrict__ x, const float* __restrict__ g1, const float* __restrict__ be1,
    u16* __restrict__ h){
  __shared__ float2 A[1024], Bb[1024];  // 16 KB
  int t = threadIdx.x, id = blockIdx.x;
  int b = id / 2049, k = id - b * 2049;
  int idx = t * 4;
  if (k == 2048){
    float4 v = *(const float4*)(Zny + b * 1024 + idx);
    A[idx + 0] = make_float2(v.x, 0.f); A[idx + 1] = make_float2(v.y, 0.f);
    A[idx + 2] = make_float2(v.z, 0.f); A[idx + 3] = make_float2(v.w, 0.f);
  } else {
    uint4 zv = *(const uint4*)(Z2 + ((size_t)b * 2048 + k) * 1024 + idx);
    A[idx + 0] = make_float2(bf2f((u16)(zv.x & 0xffffu)), bf2f((u16)(zv.x >> 16)));
    A[idx + 1] = make_float2(bf2f((u16)(zv.y & 0xffffu)), bf2f((u16)(zv.y >> 16)));
    A[idx + 2] = make_float2(bf2f((u16)(zv.z & 0xffffu)), bf2f((u16)(zv.z >> 16)));
    A[idx + 3] = make_float2(bf2f((u16)(zv.w & 0xffffu)), bf2f((u16)(zv.w >> 16)));
  }
  __syncthreads();
  float2* R = fft_r4<10>(A, Bb, t);
  int rowA = b * 4096 + k;
  bool two = (k >= 1) && (k <= 2047);
  int rowB = b * 4096 + (4096 - k);
  float4 xa = *(const float4*)(x + (size_t)rowA * 1024 + idx);
  float vA0 = R[idx + 0].x + xa.x, vA1 = R[idx + 1].x + xa.y;
  float vA2 = R[idx + 2].x + xa.z, vA3 = R[idx + 3].x + xa.w;
  float vB0 = 0.f, vB1 = 0.f, vB2 = 0.f, vB3 = 0.f;
  if (two){
    float4 xb = *(const float4*)(x + (size_t)rowB * 1024 + idx);
    vB0 = R[(1024 - (idx + 0)) & 1023].x + xb.x;   // Re(Y[4096-k,m]) = Re(Y[k,(1024-m)&1023])
    vB1 = R[(1024 - (idx + 1)) & 1023].x + xb.y;
    vB2 = R[(1024 - (idx + 2)) & 1023].x + xb.z;
    vB3 = R[(1024 - (idx + 3)) & 1023].x + xb.w;
  }
  float mA, iA, mB, iB;
  block_stats4(vA0 + vA1 + vA2 + vA3, vA0 * vA0 + vA1 * vA1 + vA2 * vA2 + vA3 * vA3,
               vB0 + vB1 + vB2 + vB3, vB0 * vB0 + vB1 * vB1 + vB2 * vB2 + vB3 * vB3,
               t, mA, iA, mB, iB);
  float4 gv = *(const float4*)(g1 + idx);
  float4 bv = *(const float4*)(be1 + idx);
  ushort4 oA;
  oA.x = f2bf((vA0 - mA) * iA * gv.x + bv.x);
  oA.y = f2bf((vA1 - mA) * iA * gv.y + bv.y);
  oA.z = f2bf((vA2 - mA) * iA * gv.z + bv.z);
  oA.w = f2bf((vA3 - mA) * iA * gv.w + bv.w);
  *(ushort4*)(h + (size_t)rowA * 1024 + idx) = oA;
  if (two){
    ushort4 oB;
    oB.x = f2bf((vB0 - mB) * iB * gv.x + bv.x);
    oB.y = f2bf((vB1 - mB) * iB * gv.y + bv.y);
    oB.z = f2bf((vB2 - mB) * iB * gv.z + bv.z);
    oB.w = f2bf((vB3 - mB) * iB * gv.w + bv.w);
    *(ushort4*)(h + (size_t)rowB * 1024 + idx) = oB;
  }
}

// K3: final LayerNorm on y rows (bf16) -> out (fp32)
__global__ __launch_bounds__(256) void ln_rows(const u16* __restrict__ yv, const float* __restrict__ g,
    const float* __restrict__ be, float* __restrict__ o){
  int t = threadIdx.x;
  size_t base = (size_t)blockIdx.x * 1024;
  int idx = t * 4;
  ushort4 v4 = *(const ushort4*)(yv + base + idx);
  float v0 = bf2f(v4.x), v1 = bf2f(v4.y), v2 = bf2f(v4.z), v3 = bf2f(v4.w);
  float mA, iA, mB, iB;
  block_stats4(v0 + v1 + v2 + v3, v0 * v0 + v1 * v1 + v2 * v2 + v3 * v3, 0.f, 0.f, t, mA, iA, mB, iB);
  float4 gv = *(const float4*)(g + idx);
  float4 bv = *(const float4*)(be + idx);
  float4 ov;
  ov.x = (v0 - mA) * iA * gv.x + bv.x;
  ov.y = (v1 - mA) * iA * gv.y + bv.y;
  ov.z = (v2 - mA) * iA * gv.z + bv.z;
  ov.w = (v3 - mA) * iA * gv.w + bv.w;
  *(float4*)(o + base + idx) = ov;
}

// ======================= persistent 256x256 8-phase bf16 GEMM, r7: pipelined reads ======
// C = epi(A @ B^T + bias); A: MxK bf16, Bm: NxK bf16. 512 thr = 8 waves (2M x 4N),
// per-wave 128x64 out, acc[8][4] 16x16x32 MFMA. BK=64 in two 32-k slabs; LDS 128 KiB.
// r7 theory (explains r2-r5 nulls + r5's LDS-cost amplification): per K-tile the CU pays
// MFMA 2483 cyc + LDS 2311 cyc SERIALIZED because frags are ds_read in the same phase
// window that consumes them (post-barrier lgkm drain of 8 waves' bursts = ~1150 cyc/phase).
// Fix: CROSS-PHASE pipelining with 2 persistent frag sets: E=ks0 frags, F=ks1 frags.
//   P0: read F(kt,ks1)    [consumed P2/P3]; stage B(kt+1)ks1; bar; MFMA(E nf01); bar
//   P1:                    stage A(kt+2)ks0; bar; MFMA(E nf23); bar
//   P2: vmcnt(6) -> read E'(kt+1,ks0) [consumed next P0/P1]; stage B(kt+2)ks0; bar; MFMA(F nf01); bar
//   P3:                    stage A(kt+2)ks1; bar; MFMA(F nf23); vmcnt(6); bar
// Every burst drains under >=2 MFMA phases (1240 cyc >= 1150). Compiler emits counted
// lgkmcnt(12) before each cluster (consumed set older than the 12 just-issued reads).
// P2's vmcnt(6) proves (kt+1)-ks0 landed: outstanding order [Aks1(kt+1),Bks1(kt+1),
// Aks0(kt+2)] = newest 3 units = 6 instrs; everything older (incl kt+1-ks0) retired.
// Overwrite-safety: each LDS region's reads are lgkm-retired before the consuming MFMA
// cluster, which precedes the region's overwriting stage by >=1 barrier (checked per
// region). Seam: post-epilogue vmcnt(6) leaves only newest stores -> prestage landed ->
// E(kt=0) re-read safe. Boundary vmcnt(6), partitions, T2 swizzle, epilogue unchanged.
typedef const __attribute__((address_space(1))) void* as1cp;
typedef __attribute__((address_space(3))) void* as3p;
DI void async_copy16(const void* g, void* l){
  __builtin_amdgcn_global_load_lds((as1cp)(u64)g, (as3p)(u32)(u64)l, 16, 0, 0);
}
DI void bar(){
  asm volatile("" ::: "memory");
  __builtin_amdgcn_s_barrier();
  asm volatile("" ::: "memory");
}

template<int DOGELU>
__global__ __launch_bounds__(512, 2) void gemm256(const u16* __restrict__ A, const u16* __restrict__ Bm,
    const float* __restrict__ bias, const u16* __restrict__ resid, u16* __restrict__ C,
    int M, int N, int K, int gn_shift, int npg_shift, int mpg, int bpg, int npt)
{
  __shared__ u16 sA[2][2][8192];   // [buf][ks][256 rows x 32 k]
  __shared__ u16 sB[2][2][8192];
  int t = threadIdx.x, wv = t >> 6, ln = t & 63;

  int bid = blockIdx.x;
  int c8 = bid & 7, j0 = bid >> 3;
  int ng = c8 & ((1 << gn_shift) - 1);
  int mg = c8 >> gn_shift;
  int npg_m1 = (1 << npg_shift) - 1;

  int wm = wv >> 2, wn = wv & 3;       // wave -> (m-half, n-quarter) of the 256x256 tile
  int lt = ln & 15;
  int cs = (((ln >> 4) ^ ((ln >> 1) & 3)) << 3);      // swizzled k-chunk (u16 units)
  int arow = (wm * 128 + lt) * 32 + cs;
  int brow = (wn * 64 + lt) * 32 + cs;
  int srow = wv * 32 + (ln >> 2);
  int gch  = ((ln & 3) ^ ((srow >> 1) & 3)) << 3;     // inverse swizzle on global source
  int ldof = wv * 1024 + ln * 8;
  int NT = K >> 6;

  #define STAGE(g0, g1, kc, unit) do{ \
    async_copy16((g0) + (kc), (unit) + ldof); \
    async_copy16((g1) + (kc), (unit) + 512 + ldof); }while(0)
  #define PROLOGUE() do{ \
    STAGE(gA0, gA1, 0,  &sA[0][0][0]); \
    STAGE(gB0, gB1, 0,  &sB[0][0][0]); \
    STAGE(gA0, gA1, 32, &sA[0][1][0]); \
    STAGE(gB0, gB1, 32, &sB[0][1][0]); \
    STAGE(gA0, gA1, 64, &sA[1][0][0]); \
    STAGE(gB0, gB1, 64, &sB[1][0][0]); \
    STAGE(gA0, gA1, 96, &sA[1][1][0]); }while(0)
  // read a 12-frag set (8 A + 4 B) from one k-slab's LDS regions
  #define RDSET(dstA, dstB, asrc, bsrc) do{ \
    _Pragma("unroll") \
    for (int mf = 0; mf < 8; mf++) dstA[mf] = *(const bf16x8*)((asrc) + arow + mf * 512); \
    _Pragma("unroll") \
    for (int nf = 0; nf < 4; nf++) dstB[nf] = *(const bf16x8*)((bsrc) + brow + nf * 512); }while(0)
  #define MMH(aS, bS, n0_, n1_) do{ \
    _Pragma("unroll") \
    for (int mf = 0; mf < 8; mf++){ \
      acc[mf][n0_] = __builtin_amdgcn_mfma_f32_16x16x32_bf16(aS[mf], bS[n0_], acc[mf][n0_], 0, 0, 0); \
      acc[mf][n1_] = __builtin_amdgcn_mfma_f32_16x16x32_bf16(aS[mf], bS[n1_], acc[mf][n1_], 0, 0, 0); \
    } }while(0)

  // tile 0 pointers + initial prologue
  int jt = j0;
  int n0 = (((ng << npg_shift) + (jt & npg_m1)) << 8);
  int m0 = ((mg * mpg + (jt >> npg_shift)) << 8);
  const u16* gA0 = A  + (size_t)(m0 + srow) * K + gch;
  const u16* gA1 = gA0 + (size_t)16 * K;
  const u16* gB0 = Bm + (size_t)(n0 + srow) * K + gch;
  const u16* gB1 = gB0 + (size_t)16 * K;
  PROLOGUE();
  asm volatile("s_waitcnt vmcnt(6)" ::: "memory");   // tile0 resident; tile1 in flight
  bar();

  bf16x8 aE[8], bE[4], aF[8], bF[4];   // persistent frag sets: E=ks0, F=ks1

  for (int s = 0; s < npt; ++s){
    f32x4 acc[8][4];
    #pragma unroll
    for (int mf = 0; mf < 8; mf++)
      #pragma unroll
      for (int nf = 0; nf < 4; nf++) acc[mf][nf] = (f32x4){0.f, 0.f, 0.f, 0.f};

    // tile prologue: read E = (kt=0, ks0) frags (tile0 landed per vmcnt above / seam wait)
    RDSET(aE, bE, &sA[0][0][0], &sB[0][0][0]);

    for (int kt = 0; kt < NT; ++kt){
      int buf = kt & 1;
      u16* a0s = &sA[buf][0][0];
      u16* a1s = &sA[buf][1][0];
      u16* b0s = &sB[buf][0][0];
      u16* b1s = &sB[buf][1][0];
      u16* an  = &sA[buf ^ 1][0][0];     // (kt+1) ks0 regions
      u16* bn  = &sB[buf ^ 1][0][0];
      u16* bn1 = &sB[buf ^ 1][1][0];     // B(kt+1)-ks1 dest (other buf)
      bool st1 = (kt + 1) < NT;
      bool st2 = (kt + 2) < NT;
      int kb1 = (kt + 1) << 6, kb2 = (kt + 2) << 6;

      // ---- P0: read F=(kt,ks1); stage B(kt+1)ks1; MFMA(E, nf0-1)
      RDSET(aF, bF, a1s, b1s);
      if (st1) STAGE(gB0, gB1, kb1 + 32, bn1);
      bar();
      __builtin_amdgcn_s_setprio(1);
      MMH(aE, bE, 0, 1);                 // lgkmcnt(12): E reads (older) retired, F in flight
      __builtin_amdgcn_s_setprio(0);
      bar();

      // ---- P1: stage A(kt+2)ks0; MFMA(E, nf2-3)
      if (st2) STAGE(gA0, gA1, kb2, a0s);   // overwrites (kt,ks0)-A: E reads retired at P0's lgkm
      bar();
      __builtin_amdgcn_s_setprio(1);
      MMH(aE, bE, 2, 3);
      __builtin_amdgcn_s_setprio(0);
      bar();

      // ---- P2: vmcnt(6) -> read E'=(kt+1,ks0); stage B(kt+2)ks0; MFMA(F, nf0-1)
      if (st1){
        asm volatile("s_waitcnt vmcnt(6)" ::: "memory");  // (kt+1)-ks0 A+B landed (oldest units)
        RDSET(aE, bE, an, bn);
      }
      if (st2) STAGE(gB0, gB1, kb2, b0s);   // overwrites (kt,ks0)-B: retired at prev lgkm
      bar();
      __builtin_amdgcn_s_setprio(1);
      MMH(aF, bF, 0, 1);                 // lgkmcnt(12): F (older) retired, E' in flight
      __builtin_amdgcn_s_setprio(0);
      bar();

      // ---- P3: stage A(kt+2)ks1; MFMA(F, nf2-3); boundary vmcnt
      if (st2) STAGE(gA0, gA1, kb2 + 32, a1s);  // overwrites (kt,ks1)-A: F retired at P2's lgkm
      bar();
      __builtin_amdgcn_s_setprio(1);
      MMH(aF, bF, 2, 3);
      __builtin_amdgcn_s_setprio(0);
      if (st1) asm volatile("s_waitcnt vmcnt(6)" ::: "memory");  // tile kt+1 landed
      else     asm volatile("s_waitcnt vmcnt(0)" ::: "memory");  // tail: drain before LDS reuse
      bar();
    }

    // prestage tile s+1 BEFORE epilogue: staging latency hides under epilogue VALU.
    int em0 = m0, en0 = n0;
    if (s + 1 < npt){
      jt = j0 + (s + 1) * bpg;
      n0 = (((ng << npg_shift) + (jt & npg_m1)) << 8);
      m0 = ((mg * mpg + (jt >> npg_shift)) << 8);
      gA0 = A  + (size_t)(m0 + srow) * K + gch;
      gA1 = gA0 + (size_t)16 * K;
      gB0 = Bm + (size_t)(n0 + srow) * K + gch;
      gB1 = gB0 + (size_t)16 * K;
      PROLOGUE();
    }

    // epilogue: D col = lane&15, row = (lane>>4)*4 + reg  [m89-verified mapping]
    int colq = lt, rq = ln >> 4;
    #pragma unroll
    for (int mf = 0; mf < 8; mf++){
      int mr = em0 + wm * 128 + mf * 16 + rq * 4;
      #pragma unroll
      for (int nf = 0; nf < 4; nf++){
        int col = en0 + wn * 64 + nf * 16 + colq;
        float bv = bias[col];
        #pragma unroll
        for (int i = 0; i < 4; i++){
          float v = acc[mf][nf][i] + bv;
          if (DOGELU){
            v = gelu_fast(v);
          } else {
            v += bf2f(resid[(size_t)(mr + i) * N + col]);
          }
          C[(size_t)(mr + i) * N + col] = f2bf(v);
        }
      }
    }

    if (s + 1 < npt){
      // in-order vmcnt retirement: vmcnt(6) leaves only the 6 newest stores in flight;
      // all 14 prestage instrs (older) retired -> next tile's E-read is safe.
      asm volatile("s_waitcnt vmcnt(6)" ::: "memory");
      bar();
    }
  }
  #undef MMH
  #undef RDSET
  #undef PROLOGUE
  #undef STAGE
}

// ---------------- orchestration ----------------
// B=4, S=4096, H=1024, fp32 I/O. ws >= 209 MiB proven (round-3 nch=1 FETCH signature).
static inline int ilog2(int v){ int s = 0; while ((1 << s) < v) ++s; return s; }

extern "C" void kernel_launch(void* const* d_in, const int* in_sizes, int n_in,
                              void* d_out, int out_size, void* d_ws, size_t ws_size,
                              hipStream_t stream){
  const float* x   = (const float*)d_in[0];
  const float* w1  = (const float*)d_in[1];
  const float* b1  = (const float*)d_in[2];
  const float* w2  = (const float*)d_in[3];
  const float* b2  = (const float*)d_in[4];
  const float* g1  = (const float*)d_in[5];
  const float* be1 = (const float*)d_in[6];
  const float* g2  = (const float*)d_in[7];
  const float* be2 = (const float*)d_in[8];
  float* out = (float*)d_out;
  char* ws = (char*)d_ws;
  const size_t MB = (size_t)1 << 20;
  float* xT  = (float*)(ws);
  u32*  ZT2  = (u32*)(ws + 64 * MB);
  float* Zny = (float*)(ws + 96 * MB);
  u32*  Z2   = (u32*)(ws);
  u16*  h    = (u16*)(ws + 32 * MB);
  u16*  w1T  = (u16*)(ws + 64 * MB);
  u16*  w2T  = (u16*)(ws + 72 * MB);
  u16*  u    = (u16*)(ws + 80 * MB);
  u16*  y    = (u16*)(ws);
  dim3 blk(256, 1, 1);
  dim3 blk2(512, 1, 1);

  // mixing: seq FFT (packed real pairs) -> Hermitian half -> hidden FFT (+x, LN1)
  transpose_u32<<<dim3(16, 64, 4), blk, 0, stream>>>((const u32*)x, (u32*)xT, 4096, 1024);
  fft_seq      <<<dim3(2048, 1, 1), blk, 0, stream>>>(xT, ZT2, Zny);
  transpose_u32<<<dim3(32, 16, 4), blk, 0, stream>>>(ZT2, Z2, 1024, 2048);
  fft_hid_ln   <<<dim3(4 * 2049, 1, 1), blk, 0, stream>>>(Z2, Zny, x, g1, be1, h);

  // FFN (both weight transposes in one launch)
  transpose_w<<<dim3(64, 16, 2), blk, 0, stream>>>(w1, w1T, w2, w2T);
  int nch = (ws_size >= (size_t)209 * MB) ? 1 : (ws_size >= (size_t)145 * MB) ? 2 : 4;
  int Mc = 16384 / nch;
  for (int ch = 0; ch < nch; ++ch){
    const u16* hch = h + (size_t)ch * Mc * 1024;
    u16* ych = y + (size_t)ch * Mc * 1024;
    // gemm1: M x 4096, K=1024, GN=4 n-groups (B-slice 2MB L2-locked)
    {
      int tm = Mc >> 8, tn = 16, gn = 2;
      int tiles = tm * tn;
      int grid = tiles < 256 ? tiles : 256;
      int npt = tiles / grid, bpg = grid >> 3;
      int npgs = ilog2(tn >> gn);
      int mpg = tm >> (3 - gn);
      gemm256<1><<<dim3(grid), blk2, 0, stream>>>(hch, w1T, b1, (const u16*)nullptr, u,
                                                  Mc, 4096, 1024, gn, npgs, mpg, bpg, npt);
    }
    // gemm2: M x 1024, K=4096, GN=1 (A=u streamed once per XCD m-slice, B L3-hot)
    {
      int tm = Mc >> 8, tn = 4, gn = 0;
      int tiles = tm * tn;
      int grid = tiles < 256 ? tiles : 256;
      int npt = tiles / grid, bpg = grid >> 3;
      int npgs = ilog2(tn >> gn);
      int mpg = tm >> (3 - gn);
      gemm256<0><<<dim3(grid), blk2, 0, stream>>>(u, w2T, b2, hch, ych,
                                                  Mc, 1024, 4096, gn, npgs, mpg, bpg, npt);
    }
  }
  ln_rows<<<dim3(16384, 1, 1), blk, 0, stream>>>(y, g2, be2, out);
}